// Round 12
// baseline (25.572 us; speedup 1.0000x reference)
//
#include <hip/hip_runtime.h>

#define BB 16
#define NN 768
#define NBOND 6144
#define BOTOLF 0.001f

#define THREADS        192          // 3 waves; 2 bonds per thread
#define BLKS_PER_BATCH 16
#define BONDS_PER_BLK  384
#define NPART          (BB * BLKS_PER_BATCH)   // 256 partial force arrays
#define FELEMS         (NN * 3)     // 2304 floats per partial
#define F4             (FELEMS / 4) // 576 float4s per partial

typedef float f32x2 __attribute__((ext_vector_type(2)));

// ---- padded LDS weight layout (floats) ----
#define L_FM_WI 0      // 3 rows x 12
#define L_FM_BI 36     // 12
#define L_FM_W  48     // 5 x 9 x 12
#define L_FM_B  588    // 5 x 12
#define L_FM_WO 648    // 9 rows x 4
#define L_FM_BO 684    // 4
#define L_FE_WI 688    // 3 x 8
#define L_FE_BI 712    // 8
#define L_FE_W  720    // 5 x 8 x 8
#define L_FE_B  1040   // 5 x 8
#define L_FE_WO 1080   // 8
#define L_FE_BO 1088   // 1 (+3 pad)
#define WTOT    1092

// fast approx (v_rcp_f32 / v_rsq_f32): ~1 ulp, fine vs 1-2% tolerance
__device__ __forceinline__ float frcp(float x)  { return __builtin_amdgcn_rcpf(x); }
__device__ __forceinline__ float frsq(float x)  { return __builtin_amdgcn_rsqf(x); }

__device__ __forceinline__ float sigf(float z) {
    return frcp(1.0f + __expf(-z));          // v_exp + v_rcp, no VCC div sequence
}

__device__ __forceinline__ f32x2 sig2(f32x2 z) {
    float s = sigf(z.x);
    f32x2 r;
    r.x = s;
    r.y = s * (1.0f - s) * z.y;
    return r;
}

// bop value + d(bop)/dr. r0i = 1/r0 (compile-time const), inv_r precomputed.
__device__ __forceinline__ f32x2 bop_calc(float r, float inv_r, float bo1, float r0i, int ibo2)
{
    float t = r * r0i;
    float t2 = t * t;
    float p;
    if (ibo2 == 6)      p = t2 * t2 * t2;
    else if (ibo2 == 5) p = t2 * t2 * t;
    else                p = t2 * t2;
    float e = (1.0f + BOTOLF) * __expf(bo1 * p);
    float de_dr = e * bo1 * (float)ibo2 * p * inv_r;

    const float rmin = BOTOLF, rmax = 2.0f * BOTOLF;
    float T, dT;
    if (e > rmax) { T = 1.0f; dT = 0.0f; }
    else if (e > rmin) {
        const float rterm = -1.0e9f;           // 1/(rmin-rmax)^3
        float rd   = rmin - e;
        float trm1 = rmin + 2.0f * e - 3.0f * rmax;
        T  = rterm * rd * rd * trm1;
        dT = rterm * 2.0f * rd * (rd - trm1);
    } else { T = 0.0f; dT = 0.0f; }

    f32x2 out;
    out.x = T * (e - BOTOLF);
    out.y = (dT * (e - BOTOLF) + T) * de_dr;
    return out;
}

// dense layer for 2 bonds: each weight read once, applied to both bonds.
template<int NIN, int NOUT, int PAD>
__device__ __forceinline__ void dense2(const float* __restrict__ wb, const float* __restrict__ bb,
                                       const f32x2* __restrict__ hA, const f32x2* __restrict__ hB,
                                       f32x2* __restrict__ oA, f32x2* __restrict__ oB)
{
    f32x2 zA[NOUT], zB[NOUT];
    #pragma unroll
    for (int j = 0; j < NOUT; j++) {
        float bv = bb[j];
        zA[j].x = bv; zA[j].y = 0.0f;
        zB[j].x = bv; zB[j].y = 0.0f;
    }
    #pragma unroll
    for (int k = 0; k < NIN; k++) {
        const float* row = wb + k * PAD;
        #pragma unroll
        for (int j = 0; j < NOUT; j++) {
            float wv = row[j];
            zA[j] += hA[k] * wv;
            zB[j] += hB[k] * wv;
        }
    }
    #pragma unroll
    for (int j = 0; j < NOUT; j++) { oA[j] = sig2(zA[j]); oB[j] = sig2(zB[j]); }
}

__global__ __launch_bounds__(THREADS) void reaxff_bond_kernel(
    const float* __restrict__ x, const float* __restrict__ cell, const float* __restrict__ rcell,
    const float* __restrict__ fm_wi, const float* __restrict__ fm_bi,
    const float* __restrict__ fm_w,  const float* __restrict__ fm_b,
    const float* __restrict__ fm_wo, const float* __restrict__ fm_bo,
    const float* __restrict__ fe_wi, const float* __restrict__ fe_bi,
    const float* __restrict__ fe_w,  const float* __restrict__ fe_b,
    const float* __restrict__ fe_wo, const float* __restrict__ fe_bo,
    const float* __restrict__ desi_p, const int* __restrict__ bdid,
    float* __restrict__ fpart,        // [NPART][FELEMS]
    float* __restrict__ epart)        // [NPART]
{
    __shared__ alignas(16) float w[WTOT];
    __shared__ alignas(16) float fsh[FELEMS];
    __shared__ float esum[THREADS / 64];
    const int tid = threadIdx.x;

    const int b     = blockIdx.x / BLKS_PER_BATCH;
    const int kbase = (blockIdx.x % BLKS_PER_BATCH) * BONDS_PER_BLK + tid;

    // ---- issue bond-data loads EARLY (latency hides under staging) ----
    int aidx[2], ajdx[2];
    float xiv[2][3], xjv[2][3];
    #pragma unroll
    for (int q = 0; q < 2; q++) {
        const int2 bij = ((const int2*)bdid)[kbase + q * THREADS];
        aidx[q] = bij.x; ajdx[q] = bij.y;
        const float* xi = x + (size_t)(b * NN + bij.x) * 3;
        const float* xj = x + (size_t)(b * NN + bij.y) * 3;
        xiv[q][0] = xi[0]; xiv[q][1] = xi[1]; xiv[q][2] = xi[2];
        xjv[q][0] = xj[0]; xjv[q][1] = xj[1]; xjv[q][2] = xj[2];
    }

    // ---- zero LDS force accumulator (float4) ----
    {
        float4* f4 = (float4*)fsh;
        const float4 zz = {0.0f, 0.0f, 0.0f, 0.0f};
        #pragma unroll 1
        for (int i = tid; i < F4; i += THREADS) f4[i] = zz;
    }

    // ---- stage weights to LDS, padded rows (strided loops) ----
    #pragma unroll 1
    for (int idx = tid; idx < 36; idx += THREADS) {      // fm_wi 3x9 -> 3x12
        int r = idx / 12, c = idx % 12;
        w[L_FM_WI + idx] = (c < 9) ? fm_wi[r * 9 + c] : 0.0f;
    }
    #pragma unroll 1
    for (int idx = tid; idx < 12; idx += THREADS)
        w[L_FM_BI + idx] = (idx < 9) ? fm_bi[idx] : 0.0f;
    #pragma unroll 1
    for (int idx = tid; idx < 540; idx += THREADS) {     // fm_w 5x9x9 -> 5x9x12
        int l = idx / 108, rem = idx % 108, r = rem / 12, c = rem % 12;
        w[L_FM_W + idx] = (c < 9) ? fm_w[l * 81 + r * 9 + c] : 0.0f;
    }
    #pragma unroll 1
    for (int idx = tid; idx < 60; idx += THREADS) {      // fm_b 5x9 -> 5x12
        int l = idx / 12, c = idx % 12;
        w[L_FM_B + idx] = (c < 9) ? fm_b[l * 9 + c] : 0.0f;
    }
    #pragma unroll 1
    for (int idx = tid; idx < 36; idx += THREADS) {      // fm_wo 9x3 -> 9x4
        int r = idx / 4, c = idx % 4;
        w[L_FM_WO + idx] = (c < 3) ? fm_wo[r * 3 + c] : 0.0f;
    }
    if (tid < 4)  w[L_FM_BO + tid] = (tid < 3) ? fm_bo[tid] : 0.0f;
    if (tid < 24) w[L_FE_WI + tid] = fe_wi[tid];
    if (tid < 8)  w[L_FE_BI + tid] = fe_bi[tid];
    #pragma unroll 1
    for (int idx = tid; idx < 320; idx += THREADS) w[L_FE_W + idx] = fe_w[idx];
    if (tid < 40) w[L_FE_B + tid]  = fe_b[tid];
    if (tid < 8)  w[L_FE_WO + tid] = fe_wo[tid];
    if (tid == 0) { w[L_FE_BO] = fe_bo[0]; w[L_FE_BO+1]=0; w[L_FE_BO+2]=0; w[L_FE_BO+3]=0; }
    __syncthreads();

    const float* cb = cell  + b * 9;
    const float* rb = rcell + b * 9;
    const float D  = desi_p[0];

    // ---- geometry for both bonds ----
    float rr[2], irr[2], mvx[2], mvy[2], mvz[2];
    #pragma unroll
    for (int q = 0; q < 2; q++) {
        float u0 = xiv[q][0] - xjv[q][0];
        float u1 = xiv[q][1] - xjv[q][1];
        float u2 = xiv[q][2] - xjv[q][2];

        float f0 = u0 * rb[0] + u1 * rb[3] + u2 * rb[6];
        float f1 = u0 * rb[1] + u1 * rb[4] + u2 * rb[7];
        float f2 = u0 * rb[2] + u1 * rb[5] + u2 * rb[8];
        f0 = (f0 - 0.5f > 0.0f) ? f0 - 1.0f : f0;  f0 = (f0 + 0.5f < 0.0f) ? f0 + 1.0f : f0;
        f1 = (f1 - 0.5f > 0.0f) ? f1 - 1.0f : f1;  f1 = (f1 + 0.5f < 0.0f) ? f1 + 1.0f : f1;
        f2 = (f2 - 0.5f > 0.0f) ? f2 - 1.0f : f2;  f2 = (f2 + 0.5f < 0.0f) ? f2 + 1.0f : f2;
        float v0 = f0 * cb[0] + f1 * cb[3] + f2 * cb[6];
        float v1 = f0 * cb[1] + f1 * cb[4] + f2 * cb[7];
        float v2 = f0 * cb[2] + f1 * cb[5] + f2 * cb[8];

        float r2sum = v0 * v0 + v1 * v1 + v2 * v2 + 1e-8f;
        float inv_r = frsq(r2sum);
        rr[q]  = r2sum * inv_r;
        irr[q] = inv_r;

        float cv0 = cb[0] * v0 + cb[1] * v1 + cb[2] * v2;
        float cv1 = cb[3] * v0 + cb[4] * v1 + cb[5] * v2;
        float cv2 = cb[6] * v0 + cb[7] * v1 + cb[8] * v2;
        mvx[q] = rb[0] * cv0 + rb[1] * cv1 + rb[2] * cv2;
        mvy[q] = rb[3] * cv0 + rb[4] * cv1 + rb[5] * cv2;
        mvz[q] = rb[6] * cv0 + rb[7] * cv1 + rb[8] * cv2;
    }

    // ---- features ----
    f32x2 hA[9], hB[9], tA[9], tB[9];
    hA[0] = bop_calc(rr[0], irr[0], -0.077f, 1.0f / 1.39f, 6);
    hA[1] = bop_calc(rr[0], irr[0], -0.15f,  1.0f / 1.30f, 5);
    hA[2] = bop_calc(rr[0], irr[0], -0.30f,  1.0f / 1.25f, 4);
    hB[0] = bop_calc(rr[1], irr[1], -0.077f, 1.0f / 1.39f, 6);
    hB[1] = bop_calc(rr[1], irr[1], -0.15f,  1.0f / 1.30f, 5);
    hB[2] = bop_calc(rr[1], irr[1], -0.30f,  1.0f / 1.25f, 4);

    // ---- MLP fm: 3 -> 9 -> (5x)9 -> 3 ----
    dense2<3, 9, 12>(w + L_FM_WI, w + L_FM_BI, hA, hB, tA, tB);
    #pragma unroll
    for (int j = 0; j < 9; j++) { hA[j] = tA[j]; hB[j] = tB[j]; }
    #pragma unroll 1
    for (int l = 0; l < 5; l++) {
        dense2<9, 9, 12>(w + L_FM_W + l * 108, w + L_FM_B + l * 12, hA, hB, tA, tB);
        #pragma unroll
        for (int j = 0; j < 9; j++) { hA[j] = tA[j]; hB[j] = tB[j]; }
    }
    f32x2 boA[3], boB[3];
    dense2<9, 3, 4>(w + L_FM_WO, w + L_FM_BO, hA, hB, boA, boB);

    // ---- MLP fe: 3 -> 8 -> (5x)8 -> 1 ----
    f32x2 gA[8], gB[8], sA[8], sB[8];
    dense2<3, 8, 8>(w + L_FE_WI, w + L_FE_BI, boA, boB, gA, gB);
    #pragma unroll 1
    for (int l = 0; l < 5; l++) {
        dense2<8, 8, 8>(w + L_FE_W + l * 64, w + L_FE_B + l * 8, gA, gB, sA, sB);
        #pragma unroll
        for (int j = 0; j < 8; j++) { gA[j] = sA[j]; gB[j] = sB[j]; }
    }
    f32x2 zA, zB;
    zA.x = w[L_FE_BO]; zA.y = 0.0f;
    zB.x = w[L_FE_BO]; zB.y = 0.0f;
    #pragma unroll
    for (int kk = 0; kk < 8; kk++) {
        float wv = w[L_FE_WO + kk];
        zA += gA[kk] * wv;
        zB += gB[kk] * wv;
    }
    f32x2 esi[2];
    esi[0] = sig2(zA);
    esi[1] = sig2(zB);

    // ---- energy + LDS force accumulation (no global atomics) ----
    float ebd_sum = 0.0f;
    #pragma unroll
    for (int q = 0; q < 2; q++) {
        ebd_sum += -D * esi[q].x;
        float gg = -D * esi[q].y;
        float G0 = gg * mvx[q] * irr[q];
        float G1 = gg * mvy[q] * irr[q];
        float G2 = gg * mvz[q] * irr[q];
        atomicAdd(&fsh[aidx[q] * 3 + 0], -G0);
        atomicAdd(&fsh[aidx[q] * 3 + 1], -G1);
        atomicAdd(&fsh[aidx[q] * 3 + 2], -G2);
        atomicAdd(&fsh[ajdx[q] * 3 + 0],  G0);
        atomicAdd(&fsh[ajdx[q] * 3 + 1],  G1);
        atomicAdd(&fsh[ajdx[q] * 3 + 2],  G2);
    }

    // ---- per-wave energy partial ----
    float e = ebd_sum;
    #pragma unroll
    for (int off = 32; off > 0; off >>= 1) e += __shfl_down(e, off, 64);
    if ((tid & 63) == 0) esum[tid >> 6] = e;

    __syncthreads();

    // ---- write force partial, coalesced float4 ----
    float4* dst = (float4*)(fpart + (size_t)blockIdx.x * FELEMS);
    const float4* src = (const float4*)fsh;
    #pragma unroll 1
    for (int i = tid; i < F4; i += THREADS)   // 576 float4s
        dst[i] = src[i];
    if (tid == 0) {
        float es = 0.0f;
        #pragma unroll
        for (int wv = 0; wv < THREADS / 64; wv++) es += esum[wv];
        epart[blockIdx.x] = es;
    }
}

__global__ __launch_bounds__(256) void reaxff_reduce_kernel(
    const float* __restrict__ fpart, const float* __restrict__ epart,
    float* __restrict__ out)
{
    const int blk = blockIdx.x;
    const int tid = threadIdx.x;

    if (blk < (BB * F4) / 256) {              // 36 force blocks, float4 each
        const int idx4 = blk * 256 + tid;     // [0, 9216)
        const int b  = idx4 / F4;
        const int i4 = idx4 - b * F4;
        const float4* base = (const float4*)fpart + (size_t)b * BLKS_PER_BATCH * F4 + i4;
        float4 acc = {0.0f, 0.0f, 0.0f, 0.0f};
        #pragma unroll
        for (int p = 0; p < BLKS_PER_BATCH; p++) {
            float4 v = base[(size_t)p * F4];
            acc.x += v.x; acc.y += v.y; acc.z += v.z; acc.w += v.w;
        }
        ((float4*)(out + BB))[idx4] = acc;
    } else {                                  // E block
        if (tid < BB) {
            const float* base = epart + tid * BLKS_PER_BATCH;
            float acc = 0.0f;
            #pragma unroll
            for (int p = 0; p < BLKS_PER_BATCH; p++)
                acc += base[p];
            out[tid] = acc;
        }
    }
}

extern "C" void kernel_launch(void* const* d_in, const int* in_sizes, int n_in,
                              void* d_out, int out_size, void* d_ws, size_t ws_size,
                              hipStream_t stream)
{
    float* fpart = (float*)d_ws;                                // 256 x 2304 floats
    float* epart = fpart + (size_t)NPART * FELEMS;              // 256 floats
    // no d_out memset: reduce kernel plainly stores every output element

    reaxff_bond_kernel<<<dim3(NPART), dim3(THREADS), 0, stream>>>(
        (const float*)d_in[0],  (const float*)d_in[1],  (const float*)d_in[2],
        (const float*)d_in[3],  (const float*)d_in[4],  (const float*)d_in[5],
        (const float*)d_in[6],  (const float*)d_in[7],  (const float*)d_in[8],
        (const float*)d_in[9],  (const float*)d_in[10], (const float*)d_in[11],
        (const float*)d_in[12], (const float*)d_in[13], (const float*)d_in[14],
        (const float*)d_in[15], (const int*)d_in[16],
        fpart, epart);

    reaxff_reduce_kernel<<<dim3((BB * F4) / 256 + 1), dim3(256), 0, stream>>>(
        fpart, epart, (float*)d_out);
}

// Round 13
// 23.511 us; speedup vs baseline: 1.0877x; 1.0877x over previous
//
#include <hip/hip_runtime.h>

#define BB 16
#define NN 768
#define NBOND 6144
#define BOTOLF 0.001f

#define THREADS        384
#define BLKS_PER_BATCH 16
#define BONDS_PER_BLK  384          // 1 bond per thread
#define NPART          (BB * BLKS_PER_BATCH)   // 256 partial force arrays
#define FELEMS         (NN * 3)     // 2304 floats per partial
#define F4             (FELEMS / 4) // 576 float4s per partial

typedef float f32x2 __attribute__((ext_vector_type(2)));

// ---- padded LDS weight layout (floats), all rows 16B-aligned ----
#define L_FM_WI 0      // 3 rows x 12
#define L_FM_BI 36     // 12
#define L_FM_W  48     // 5 x 9 x 12
#define L_FM_B  588    // 5 x 12
#define L_FM_WO 648    // 9 rows x 4
#define L_FM_BO 684    // 4
#define L_FE_WI 688    // 3 x 8
#define L_FE_BI 712    // 8
#define L_FE_W  720    // 5 x 8 x 8
#define L_FE_B  1040   // 5 x 8
#define L_FE_WO 1080   // 8
#define L_FE_BO 1088   // 1 (+3 pad)
#define WTOT    1092

// fast approx (v_rcp_f32 / v_rsq_f32): ~1 ulp, fine vs 1-2% tolerance
__device__ __forceinline__ float frcp(float x)  { return __builtin_amdgcn_rcpf(x); }
__device__ __forceinline__ float frsq(float x)  { return __builtin_amdgcn_rsqf(x); }

__device__ __forceinline__ float sigf(float z) {
    return frcp(1.0f + __expf(-z));          // v_exp + v_rcp, no VCC div sequence
}

__device__ __forceinline__ f32x2 sig2(f32x2 z) {
    float s = sigf(z.x);
    f32x2 r;
    r.x = s;
    r.y = s * (1.0f - s) * z.y;
    return r;
}

// bop value + d(bop)/dr. r0i = 1/r0 (compile-time const), inv_r precomputed.
__device__ __forceinline__ f32x2 bop_calc(float r, float inv_r, float bo1, float r0i, int ibo2)
{
    float t = r * r0i;
    float t2 = t * t;
    float p;
    if (ibo2 == 6)      p = t2 * t2 * t2;
    else if (ibo2 == 5) p = t2 * t2 * t;
    else                p = t2 * t2;
    float e = (1.0f + BOTOLF) * __expf(bo1 * p);
    float de_dr = e * bo1 * (float)ibo2 * p * inv_r;

    const float rmin = BOTOLF, rmax = 2.0f * BOTOLF;
    float T, dT;
    if (e > rmax) { T = 1.0f; dT = 0.0f; }
    else if (e > rmin) {
        const float rterm = -1.0e9f;           // 1/(rmin-rmax)^3
        float rd   = rmin - e;
        float trm1 = rmin + 2.0f * e - 3.0f * rmax;
        T  = rterm * rd * rd * trm1;
        dT = rterm * 2.0f * rd * (rd - trm1);
    } else { T = 0.0f; dT = 0.0f; }

    f32x2 out;
    out.x = T * (e - BOTOLF);
    out.y = (dT * (e - BOTOLF) + T) * de_dr;
    return out;
}

// dense layer, 1 bond. Each padded row batch-loaded as float4s into registers
// (ds_read_b128 group issues ahead of the FMA block -> latency overlaps).
template<int NIN, int NOUT, int PAD>
__device__ __forceinline__ void dense1(const float* __restrict__ wb, const float* __restrict__ bb,
                                       const f32x2* __restrict__ h, f32x2* __restrict__ o)
{
    f32x2 z[NOUT];
    {
        float4 b4[PAD / 4];
        #pragma unroll
        for (int v = 0; v < PAD / 4; v++) b4[v] = ((const float4*)bb)[v];
        const float* bs = (const float*)b4;
        #pragma unroll
        for (int j = 0; j < NOUT; j++) { z[j].x = bs[j]; z[j].y = 0.0f; }
    }
    #pragma unroll
    for (int k = 0; k < NIN; k++) {
        float4 r4[PAD / 4];
        #pragma unroll
        for (int v = 0; v < PAD / 4; v++) r4[v] = ((const float4*)(wb + k * PAD))[v];
        const float* rs = (const float*)r4;
        #pragma unroll
        for (int j = 0; j < NOUT; j++) z[j] += h[k] * rs[j];
    }
    #pragma unroll
    for (int j = 0; j < NOUT; j++) o[j] = sig2(z[j]);
}

__global__ __launch_bounds__(THREADS) void reaxff_bond_kernel(
    const float* __restrict__ x, const float* __restrict__ cell, const float* __restrict__ rcell,
    const float* __restrict__ fm_wi, const float* __restrict__ fm_bi,
    const float* __restrict__ fm_w,  const float* __restrict__ fm_b,
    const float* __restrict__ fm_wo, const float* __restrict__ fm_bo,
    const float* __restrict__ fe_wi, const float* __restrict__ fe_bi,
    const float* __restrict__ fe_w,  const float* __restrict__ fe_b,
    const float* __restrict__ fe_wo, const float* __restrict__ fe_bo,
    const float* __restrict__ desi_p, const int* __restrict__ bdid,
    float* __restrict__ fpart,        // [NPART][FELEMS]
    float* __restrict__ epart)        // [NPART]
{
    __shared__ alignas(16) float w[WTOT];
    __shared__ alignas(16) float fsh[FELEMS];
    __shared__ float esum[THREADS / 64];
    const int tid = threadIdx.x;

    const int b = blockIdx.x / BLKS_PER_BATCH;
    const int k = (blockIdx.x % BLKS_PER_BATCH) * BONDS_PER_BLK + tid;

    // ---- issue bond-data loads EARLY (latency hides under staging) ----
    const int2 bij = ((const int2*)bdid)[k];
    const int ai = bij.x, aj = bij.y;
    const float* xi = x + (size_t)(b * NN + ai) * 3;
    const float* xj = x + (size_t)(b * NN + aj) * 3;
    float xi0 = xi[0], xi1 = xi[1], xi2 = xi[2];
    float xj0 = xj[0], xj1 = xj[1], xj2 = xj[2];

    // ---- zero LDS force accumulator ----
    {
        float4* f4 = (float4*)fsh;
        const float4 zz = {0.0f, 0.0f, 0.0f, 0.0f};
        #pragma unroll 1
        for (int i = tid; i < F4; i += THREADS) f4[i] = zz;
    }

    // ---- stage weights to LDS, padded rows (strided loops: correct for any THREADS) ----
    #pragma unroll 1
    for (int idx = tid; idx < 36; idx += THREADS) {      // fm_wi 3x9 -> 3x12
        int r = idx / 12, c = idx % 12;
        w[L_FM_WI + idx] = (c < 9) ? fm_wi[r * 9 + c] : 0.0f;
    }
    #pragma unroll 1
    for (int idx = tid; idx < 12; idx += THREADS)
        w[L_FM_BI + idx] = (idx < 9) ? fm_bi[idx] : 0.0f;
    #pragma unroll 1
    for (int idx = tid; idx < 540; idx += THREADS) {     // fm_w 5x9x9 -> 5x9x12
        int l = idx / 108, rem = idx % 108, r = rem / 12, c = rem % 12;
        w[L_FM_W + idx] = (c < 9) ? fm_w[l * 81 + r * 9 + c] : 0.0f;
    }
    #pragma unroll 1
    for (int idx = tid; idx < 60; idx += THREADS) {      // fm_b 5x9 -> 5x12
        int l = idx / 12, c = idx % 12;
        w[L_FM_B + idx] = (c < 9) ? fm_b[l * 9 + c] : 0.0f;
    }
    #pragma unroll 1
    for (int idx = tid; idx < 36; idx += THREADS) {      // fm_wo 9x3 -> 9x4
        int r = idx / 4, c = idx % 4;
        w[L_FM_WO + idx] = (c < 3) ? fm_wo[r * 3 + c] : 0.0f;
    }
    if (tid < 4)  w[L_FM_BO + tid] = (tid < 3) ? fm_bo[tid] : 0.0f;
    if (tid < 24) w[L_FE_WI + tid] = fe_wi[tid];
    if (tid < 8)  w[L_FE_BI + tid] = fe_bi[tid];
    #pragma unroll 1
    for (int idx = tid; idx < 320; idx += THREADS) w[L_FE_W + idx] = fe_w[idx];
    if (tid < 40) w[L_FE_B + tid]  = fe_b[tid];
    if (tid < 8)  w[L_FE_WO + tid] = fe_wo[tid];
    if (tid == 0) { w[L_FE_BO] = fe_bo[0]; w[L_FE_BO+1]=0; w[L_FE_BO+2]=0; w[L_FE_BO+3]=0; }
    __syncthreads();

    const float* cb = cell  + b * 9;
    const float* rb = rcell + b * 9;
    const float D  = desi_p[0];

    // ---- geometry ----
    float u0 = xi0 - xj0;
    float u1 = xi1 - xj1;
    float u2 = xi2 - xj2;

    float f0 = u0 * rb[0] + u1 * rb[3] + u2 * rb[6];
    float f1 = u0 * rb[1] + u1 * rb[4] + u2 * rb[7];
    float f2 = u0 * rb[2] + u1 * rb[5] + u2 * rb[8];
    f0 = (f0 - 0.5f > 0.0f) ? f0 - 1.0f : f0;  f0 = (f0 + 0.5f < 0.0f) ? f0 + 1.0f : f0;
    f1 = (f1 - 0.5f > 0.0f) ? f1 - 1.0f : f1;  f1 = (f1 + 0.5f < 0.0f) ? f1 + 1.0f : f1;
    f2 = (f2 - 0.5f > 0.0f) ? f2 - 1.0f : f2;  f2 = (f2 + 0.5f < 0.0f) ? f2 + 1.0f : f2;
    float v0 = f0 * cb[0] + f1 * cb[3] + f2 * cb[6];
    float v1 = f0 * cb[1] + f1 * cb[4] + f2 * cb[7];
    float v2 = f0 * cb[2] + f1 * cb[5] + f2 * cb[8];

    float r2sum = v0 * v0 + v1 * v1 + v2 * v2 + 1e-8f;
    float inv_r = frsq(r2sum);               // v_rsq_f32
    float r     = r2sum * inv_r;             // sqrt = x * rsqrt(x)

    float cv0 = cb[0] * v0 + cb[1] * v1 + cb[2] * v2;
    float cv1 = cb[3] * v0 + cb[4] * v1 + cb[5] * v2;
    float cv2 = cb[6] * v0 + cb[7] * v1 + cb[8] * v2;
    float mv0 = rb[0] * cv0 + rb[1] * cv1 + rb[2] * cv2;
    float mv1 = rb[3] * cv0 + rb[4] * cv1 + rb[5] * cv2;
    float mv2 = rb[6] * cv0 + rb[7] * cv1 + rb[8] * cv2;

    // ---- features (r0 reciprocals are compile-time constants) ----
    f32x2 h[9], t[9];
    h[0] = bop_calc(r, inv_r, -0.077f, 1.0f / 1.39f, 6);
    h[1] = bop_calc(r, inv_r, -0.15f,  1.0f / 1.30f, 5);
    h[2] = bop_calc(r, inv_r, -0.30f,  1.0f / 1.25f, 4);

    // ---- MLP fm: 3 -> 9 -> (5x)9 -> 3 ----  (rolled layer loops, b128 row loads)
    dense1<3, 9, 12>(w + L_FM_WI, w + L_FM_BI, h, t);
    #pragma unroll
    for (int j = 0; j < 9; j++) h[j] = t[j];
    #pragma unroll 1
    for (int l = 0; l < 5; l++) {
        dense1<9, 9, 12>(w + L_FM_W + l * 108, w + L_FM_B + l * 12, h, t);
        #pragma unroll
        for (int j = 0; j < 9; j++) h[j] = t[j];
    }
    f32x2 bo3[3];
    dense1<9, 3, 4>(w + L_FM_WO, w + L_FM_BO, h, bo3);

    // ---- MLP fe: 3 -> 8 -> (5x)8 -> 1 ----
    f32x2 g[8], s[8];
    dense1<3, 8, 8>(w + L_FE_WI, w + L_FE_BI, bo3, g);
    #pragma unroll 1
    for (int l = 0; l < 5; l++) {
        dense1<8, 8, 8>(w + L_FE_W + l * 64, w + L_FE_B + l * 8, g, s);
        #pragma unroll
        for (int j = 0; j < 8; j++) g[j] = s[j];
    }
    f32x2 z;
    {
        float4 wo0 = ((const float4*)(w + L_FE_WO))[0];
        float4 wo1 = ((const float4*)(w + L_FE_WO))[1];
        z.x = w[L_FE_BO]; z.y = 0.0f;
        z += g[0] * wo0.x; z += g[1] * wo0.y; z += g[2] * wo0.z; z += g[3] * wo0.w;
        z += g[4] * wo1.x; z += g[5] * wo1.y; z += g[6] * wo1.z; z += g[7] * wo1.w;
    }
    f32x2 esi = sig2(z);   // {esi, d(esi)/dr}

    // ---- energy + LDS force accumulation (no global atomics) ----
    float ebd = -D * esi.x;
    float gg  = -D * esi.y;
    float G0 = gg * mv0 * inv_r;
    float G1 = gg * mv1 * inv_r;
    float G2 = gg * mv2 * inv_r;
    atomicAdd(&fsh[ai * 3 + 0], -G0);
    atomicAdd(&fsh[ai * 3 + 1], -G1);
    atomicAdd(&fsh[ai * 3 + 2], -G2);
    atomicAdd(&fsh[aj * 3 + 0],  G0);
    atomicAdd(&fsh[aj * 3 + 1],  G1);
    atomicAdd(&fsh[aj * 3 + 2],  G2);

    // ---- per-wave energy partial ----
    float e = ebd;
    #pragma unroll
    for (int off = 32; off > 0; off >>= 1) e += __shfl_down(e, off, 64);
    if ((tid & 63) == 0) esum[tid >> 6] = e;

    __syncthreads();

    // ---- write force partial, coalesced float4 ----
    float4* dst = (float4*)(fpart + (size_t)blockIdx.x * FELEMS);
    const float4* src = (const float4*)fsh;
    #pragma unroll 1
    for (int i = tid; i < F4; i += THREADS)   // 576 float4s
        dst[i] = src[i];
    if (tid == 0) {
        float es = 0.0f;
        #pragma unroll
        for (int wv = 0; wv < THREADS / 64; wv++) es += esum[wv];
        epart[blockIdx.x] = es;
    }
}

__global__ __launch_bounds__(256) void reaxff_reduce_kernel(
    const float* __restrict__ fpart, const float* __restrict__ epart,
    float* __restrict__ out)
{
    const int blk = blockIdx.x;
    const int tid = threadIdx.x;

    if (blk < (BB * F4) / 256) {              // 36 force blocks, float4 each
        const int idx4 = blk * 256 + tid;     // [0, 9216)
        const int b  = idx4 / F4;
        const int i4 = idx4 - b * F4;
        const float4* base = (const float4*)fpart + (size_t)b * BLKS_PER_BATCH * F4 + i4;
        float4 acc = {0.0f, 0.0f, 0.0f, 0.0f};
        #pragma unroll
        for (int p = 0; p < BLKS_PER_BATCH; p++) {
            float4 v = base[(size_t)p * F4];
            acc.x += v.x; acc.y += v.y; acc.z += v.z; acc.w += v.w;
        }
        ((float4*)(out + BB))[idx4] = acc;
    } else {                                  // E block
        if (tid < BB) {
            const float* base = epart + tid * BLKS_PER_BATCH;
            float acc = 0.0f;
            #pragma unroll
            for (int p = 0; p < BLKS_PER_BATCH; p++)
                acc += base[p];
            out[tid] = acc;
        }
    }
}

extern "C" void kernel_launch(void* const* d_in, const int* in_sizes, int n_in,
                              void* d_out, int out_size, void* d_ws, size_t ws_size,
                              hipStream_t stream)
{
    float* fpart = (float*)d_ws;                                // 256 x 2304 floats
    float* epart = fpart + (size_t)NPART * FELEMS;              // 256 floats
    // no d_out memset: reduce kernel plainly stores every output element

    reaxff_bond_kernel<<<dim3(NPART), dim3(THREADS), 0, stream>>>(
        (const float*)d_in[0],  (const float*)d_in[1],  (const float*)d_in[2],
        (const float*)d_in[3],  (const float*)d_in[4],  (const float*)d_in[5],
        (const float*)d_in[6],  (const float*)d_in[7],  (const float*)d_in[8],
        (const float*)d_in[9],  (const float*)d_in[10], (const float*)d_in[11],
        (const float*)d_in[12], (const float*)d_in[13], (const float*)d_in[14],
        (const float*)d_in[15], (const int*)d_in[16],
        fpart, epart);

    reaxff_reduce_kernel<<<dim3((BB * F4) / 256 + 1), dim3(256), 0, stream>>>(
        fpart, epart, (float*)d_out);
}